// Round 18
// baseline (62.392 us; speedup 1.0000x reference)
//
#include <hip/hip_runtime.h>

// CharacteristicLineEncoder: B=4096, DIM=3, L=300, S=60, P=5, E=128
// out[b,s,e] = sum_p W_lr[s,p]*relu(W_le[e,:]·x[b,:,5s+p] + b_le[e]) + b_lr[s]
//            + relu( sum_l W_gn[l]*relu(W_ge[e,:]·x[b,:,l] + b_ge[e]) + b_gn )
//
// R17 post-mortem: NT stores gave the first win (46.4->43.9); residual is
// tail-burst stores (all 12 stores/wave eligible only after the gf barrier
// -> write-buffer backpressure bursts). This round SPLITS the sweep:
//   sweep1: global partials only (wave's 60 l), barrier, gf
//   sweep2: local branch per 4-region group, 4 NT stores issued right
//           after each group -> stores spread over ~2/3 of block life.
// Same total VALU (5 pk-ops/l each sweep); x re-read hits scalar cache.
// Live accs drop 12->4 v2f -> VGPR ~<56 -> 8 waves/SIMD. All proven
// mechanics kept: e-pair v2f lanes, s_load x/weights (uniform indices),
// named accs w/ literal indices (rule #20), no min-waves arg (R4/R5).

typedef float v2f __attribute__((ext_vector_type(2)));

#define PKFMA(a, b, c) __builtin_elementwise_fma((a), (b), (c))
#define PKRELU(a)      __builtin_elementwise_max((a), (v2f)0.0f)
#define SPLAT(s)       ((v2f)(s))

__global__ __launch_bounds__(320) void cle_kernel(
    const float* __restrict__ x,     // [B,3,300]
    const float* __restrict__ W_le,  // [E,3]
    const float* __restrict__ b_le,  // [E]
    const float* __restrict__ W_lr,  // [300]
    const float* __restrict__ b_lr,  // [60]
    const float* __restrict__ W_ge,  // [E,3]
    const float* __restrict__ b_ge,  // [E]
    const float* __restrict__ W_gn,  // [300]
    const float* __restrict__ b_gn,  // [1]
    float* __restrict__ out)         // [B,60,128]
{
    const int tid  = threadIdx.x;
    const int lane = tid & 63;
    const int wq   = __builtin_amdgcn_readfirstlane(tid >> 6);  // wave 0..4, SGPR
    const int b    = blockIdx.x;
    const int e0   = lane << 1;      // this lane's e-pair

    __shared__ v2f sgp[5][64];       // per-wave global-branch partials (2.5 KB)

    const float* __restrict__ xb = x + (size_t)b * 900;   // uniform base

    // ---- sweep 1: global branch over this wave's 60 l ----
    const v2f wg0 = {W_ge[e0 * 3 + 0], W_ge[e0 * 3 + 3]};
    const v2f wg1 = {W_ge[e0 * 3 + 1], W_ge[e0 * 3 + 4]};
    const v2f wg2 = {W_ge[e0 * 3 + 2], W_ge[e0 * 3 + 5]};
    const v2f bg  = {b_ge[e0], b_ge[e0 + 1]};
    const float bgn = b_gn[0];

    v2f ga0 = SPLAT(0.f), ga1 = SPLAT(0.f);
#pragma unroll
    for (int q = 0; q < 15; ++q) {
        const int lq = wq * 60 + q * 4;      // uniform -> s_load
        const float c00 = xb[lq + 0],       c01 = xb[lq + 1];
        const float c02 = xb[lq + 2],       c03 = xb[lq + 3];
        const float c10 = xb[300 + lq + 0], c11 = xb[300 + lq + 1];
        const float c12 = xb[300 + lq + 2], c13 = xb[300 + lq + 3];
        const float c20 = xb[600 + lq + 0], c21 = xb[600 + lq + 1];
        const float c22 = xb[600 + lq + 2], c23 = xb[600 + lq + 3];
#define GEj(j) PKRELU(PKFMA(wg2, SPLAT(c2##j), PKFMA(wg1, SPLAT(c1##j), PKFMA(wg0, SPLAT(c0##j), bg))))
        ga0 = PKFMA(SPLAT(W_gn[lq + 0]), GEj(0), ga0);
        ga1 = PKFMA(SPLAT(W_gn[lq + 1]), GEj(1), ga1);
        ga0 = PKFMA(SPLAT(W_gn[lq + 2]), GEj(2), ga0);
        ga1 = PKFMA(SPLAT(W_gn[lq + 3]), GEj(3), ga1);
    }
    sgp[wq][lane] = ga0 + ga1;
    __syncthreads();

    v2f gf;
    {
        const v2f p0 = sgp[0][lane], p1 = sgp[1][lane], p2 = sgp[2][lane];
        const v2f p3 = sgp[3][lane], p4 = sgp[4][lane];
        gf = PKRELU((((p0 + p1) + (p2 + p3)) + p4) + SPLAT(bgn));
    }

    // ---- sweep 2: local branch, 4 NT stores after EACH 4-region group ----
    const v2f wl0 = {W_le[e0 * 3 + 0], W_le[e0 * 3 + 3]};
    const v2f wl1 = {W_le[e0 * 3 + 1], W_le[e0 * 3 + 4]};
    const v2f wl2 = {W_le[e0 * 3 + 2], W_le[e0 * 3 + 5]};
    const v2f bl  = {b_le[e0], b_le[e0 + 1]};

    v2f* ob2 = (v2f*)(out + (size_t)b * (60 * 128)) + lane;   // + s*64

#define LEj(j) PKRELU(PKFMA(wl2, SPLAT(c2##j), PKFMA(wl1, SPLAT(c1##j), PKFMA(wl0, SPLAT(c0##j), bl))))
#define DOQ(qi, A0, A1, A2, A3)                                                \
    {                                                                          \
        const int lq = lbase + (qi) * 4;     /* uniform -> s_load */           \
        const float c00 = xb[lq + 0],       c01 = xb[lq + 1];                  \
        const float c02 = xb[lq + 2],       c03 = xb[lq + 3];                  \
        const float c10 = xb[300 + lq + 0], c11 = xb[300 + lq + 1];            \
        const float c12 = xb[300 + lq + 2], c13 = xb[300 + lq + 3];            \
        const float c20 = xb[600 + lq + 0], c21 = xb[600 + lq + 1];            \
        const float c22 = xb[600 + lq + 2], c23 = xb[600 + lq + 3];            \
        A0 = PKFMA(SPLAT(W_lr[lq + 0]), LEj(0), A0);                           \
        A1 = PKFMA(SPLAT(W_lr[lq + 1]), LEj(1), A1);                           \
        A2 = PKFMA(SPLAT(W_lr[lq + 2]), LEj(2), A2);                           \
        A3 = PKFMA(SPLAT(W_lr[lq + 3]), LEj(3), A3);                           \
    }

#pragma unroll
    for (int g = 0; g < 3; ++g) {            // fully unrolled -> g literal
        const int lbase = wq * 60 + g * 20;
        v2f a0 = SPLAT(0.f), a1 = SPLAT(0.f), a2 = SPLAT(0.f), a3 = SPLAT(0.f);
        // element t = 4*qi + j (l = 60wq + 20g + t), region = 12wq + 4g + t/5
        DOQ(0, a0, a0, a0, a0)   // t 0..3
        DOQ(1, a0, a1, a1, a1)   // t 4..7
        DOQ(2, a1, a1, a2, a2)   // t 8..11
        DOQ(3, a2, a2, a2, a3)   // t 12..15
        DOQ(4, a3, a3, a3, a3)   // t 16..19

        const int s0 = wq * 12 + g * 4;      // uniform -> b_lr scalar
        __builtin_nontemporal_store(a0 + gf + SPLAT(b_lr[s0 + 0]), &ob2[(s0 + 0) * 64]);
        __builtin_nontemporal_store(a1 + gf + SPLAT(b_lr[s0 + 1]), &ob2[(s0 + 1) * 64]);
        __builtin_nontemporal_store(a2 + gf + SPLAT(b_lr[s0 + 2]), &ob2[(s0 + 2) * 64]);
        __builtin_nontemporal_store(a3 + gf + SPLAT(b_lr[s0 + 3]), &ob2[(s0 + 3) * 64]);
    }
}

extern "C" void kernel_launch(void* const* d_in, const int* in_sizes, int n_in,
                              void* d_out, int out_size, void* d_ws, size_t ws_size,
                              hipStream_t stream) {
    const float* x    = (const float*)d_in[0];
    const float* W_le = (const float*)d_in[1];
    const float* b_le = (const float*)d_in[2];
    const float* W_lr = (const float*)d_in[3];
    const float* b_lr = (const float*)d_in[4];
    const float* W_ge = (const float*)d_in[5];
    const float* b_ge = (const float*)d_in[6];
    const float* W_gn = (const float*)d_in[7];
    const float* b_gn = (const float*)d_in[8];
    float* out = (float*)d_out;

    cle_kernel<<<4096, 320, 0, stream>>>(x, W_le, b_le, W_lr, b_lr,
                                         W_ge, b_ge, W_gn, b_gn, out);
}

// Round 19
// 60.428 us; speedup vs baseline: 1.0325x; 1.0325x over previous
//
#include <hip/hip_runtime.h>

// CharacteristicLineEncoder: B=4096, DIM=3, L=300, S=60, P=5, E=128
// out[b,s,e] = sum_p W_lr[s,p]*relu(W_le[e,:]·x[b,:,5s+p] + b_le[e]) + b_lr[s]
//            + relu( sum_l W_gn[l]*relu(W_ge[e,:]·x[b,:,l] + b_ge[e]) + b_gn )
//
// WAVE-PER-B, ZERO BARRIERS, ZERO LDS. Lane owns e-pair {2*lane,2*lane+1}
// for an entire b -> the global-branch reduction is per-lane (gf computed
// in-register, no cross-wave exchange). Two sweeps: (1) global -> gf;
// (2) local per 4-region group with 4 NT stores issued per group ->
// stores stream through the wave's life with NO sync point (R18 lesson:
// __syncthreads drains vmcnt(0); cohort phase-lock kept stores from
// overlapping compute in every barriered variant, R2-R17 all ~sum of
// pipe times). 4 independent waves (4 b's) per 256-thread block, grid
// 1024. x via uniform s_load (scalar pipe, L2-hot on re-read); NT stores
// (R17 win). Named accs, literal indices (rule #20); no min-waves arg.

typedef float v2f __attribute__((ext_vector_type(2)));

#define PKFMA(a, b, c) __builtin_elementwise_fma((a), (b), (c))
#define PKRELU(a)      __builtin_elementwise_max((a), (v2f)0.0f)
#define SPLAT(s)       ((v2f)(s))

__global__ __launch_bounds__(256) void cle_kernel(
    const float* __restrict__ x,     // [B,3,300]
    const float* __restrict__ W_le,  // [E,3]
    const float* __restrict__ b_le,  // [E]
    const float* __restrict__ W_lr,  // [300]
    const float* __restrict__ b_lr,  // [60]
    const float* __restrict__ W_ge,  // [E,3]
    const float* __restrict__ b_ge,  // [E]
    const float* __restrict__ W_gn,  // [300]
    const float* __restrict__ b_gn,  // [1]
    float* __restrict__ out)         // [B,60,128]
{
    const int tid  = threadIdx.x;
    const int lane = tid & 63;
    const int wv   = __builtin_amdgcn_readfirstlane(tid >> 6);  // wave 0..3, SGPR
    const int b    = (blockIdx.x << 2) + wv;                    // this wave's b
    const int e0   = lane << 1;      // this lane's e-pair

    const float* __restrict__ xb = x + (size_t)b * 900;   // wave-uniform base

    // ---- sweep 1: global branch over ALL 300 l (per-lane gf, no reduce) ----
    const v2f wg0 = {W_ge[e0 * 3 + 0], W_ge[e0 * 3 + 3]};
    const v2f wg1 = {W_ge[e0 * 3 + 1], W_ge[e0 * 3 + 4]};
    const v2f wg2 = {W_ge[e0 * 3 + 2], W_ge[e0 * 3 + 5]};
    const v2f bg  = {b_ge[e0], b_ge[e0 + 1]};
    const float bgn = b_gn[0];

    v2f ga0 = SPLAT(0.f), ga1 = SPLAT(0.f), ga2 = SPLAT(0.f), ga3 = SPLAT(0.f);
#define GEj(j) PKRELU(PKFMA(wg2, SPLAT(c2##j), PKFMA(wg1, SPLAT(c1##j), PKFMA(wg0, SPLAT(c0##j), bg))))
#pragma unroll
    for (int q = 0; q < 75; ++q) {
        const int lq = q * 4;                // uniform -> s_load (batched)
        const float c00 = xb[lq + 0],       c01 = xb[lq + 1];
        const float c02 = xb[lq + 2],       c03 = xb[lq + 3];
        const float c10 = xb[300 + lq + 0], c11 = xb[300 + lq + 1];
        const float c12 = xb[300 + lq + 2], c13 = xb[300 + lq + 3];
        const float c20 = xb[600 + lq + 0], c21 = xb[600 + lq + 1];
        const float c22 = xb[600 + lq + 2], c23 = xb[600 + lq + 3];
        ga0 = PKFMA(SPLAT(W_gn[lq + 0]), GEj(0), ga0);
        ga1 = PKFMA(SPLAT(W_gn[lq + 1]), GEj(1), ga1);
        ga2 = PKFMA(SPLAT(W_gn[lq + 2]), GEj(2), ga2);
        ga3 = PKFMA(SPLAT(W_gn[lq + 3]), GEj(3), ga3);
    }
    const v2f gf = PKRELU(((ga0 + ga1) + (ga2 + ga3)) + SPLAT(bgn));

    // ---- sweep 2: local branch; 4 NT stores stream out after EACH group ----
    const v2f wl0 = {W_le[e0 * 3 + 0], W_le[e0 * 3 + 3]};
    const v2f wl1 = {W_le[e0 * 3 + 1], W_le[e0 * 3 + 4]};
    const v2f wl2 = {W_le[e0 * 3 + 2], W_le[e0 * 3 + 5]};
    const v2f bl  = {b_le[e0], b_le[e0 + 1]};

    v2f* ob2 = (v2f*)(out + (size_t)b * (60 * 128)) + lane;   // + s*64

#define LEj(j) PKRELU(PKFMA(wl2, SPLAT(c2##j), PKFMA(wl1, SPLAT(c1##j), PKFMA(wl0, SPLAT(c0##j), bl))))
#define DOQ(qi, A0, A1, A2, A3)                                                \
    {                                                                          \
        const int lq = lbase + (qi) * 4;     /* uniform -> s_load */           \
        const float c00 = xb[lq + 0],       c01 = xb[lq + 1];                  \
        const float c02 = xb[lq + 2],       c03 = xb[lq + 3];                  \
        const float c10 = xb[300 + lq + 0], c11 = xb[300 + lq + 1];            \
        const float c12 = xb[300 + lq + 2], c13 = xb[300 + lq + 3];            \
        const float c20 = xb[600 + lq + 0], c21 = xb[600 + lq + 1];            \
        const float c22 = xb[600 + lq + 2], c23 = xb[600 + lq + 3];            \
        A0 = PKFMA(SPLAT(W_lr[lq + 0]), LEj(0), A0);                           \
        A1 = PKFMA(SPLAT(W_lr[lq + 1]), LEj(1), A1);                           \
        A2 = PKFMA(SPLAT(W_lr[lq + 2]), LEj(2), A2);                           \
        A3 = PKFMA(SPLAT(W_lr[lq + 3]), LEj(3), A3);                           \
    }

#pragma unroll
    for (int g = 0; g < 15; ++g) {           // fully unrolled -> literals
        const int lbase = g * 20;
        v2f a0 = SPLAT(0.f), a1 = SPLAT(0.f), a2 = SPLAT(0.f), a3 = SPLAT(0.f);
        // element t = 4*qi + j (l = 20g + t), region = 4g + t/5
        DOQ(0, a0, a0, a0, a0)   // t 0..3
        DOQ(1, a0, a1, a1, a1)   // t 4..7
        DOQ(2, a1, a1, a2, a2)   // t 8..11
        DOQ(3, a2, a2, a2, a3)   // t 12..15
        DOQ(4, a3, a3, a3, a3)   // t 16..19

        const int s0 = g * 4;                // uniform -> b_lr scalar
        __builtin_nontemporal_store(a0 + gf + SPLAT(b_lr[s0 + 0]), &ob2[(s0 + 0) * 64]);
        __builtin_nontemporal_store(a1 + gf + SPLAT(b_lr[s0 + 1]), &ob2[(s0 + 1) * 64]);
        __builtin_nontemporal_store(a2 + gf + SPLAT(b_lr[s0 + 2]), &ob2[(s0 + 2) * 64]);
        __builtin_nontemporal_store(a3 + gf + SPLAT(b_lr[s0 + 3]), &ob2[(s0 + 3) * 64]);
    }
}

extern "C" void kernel_launch(void* const* d_in, const int* in_sizes, int n_in,
                              void* d_out, int out_size, void* d_ws, size_t ws_size,
                              hipStream_t stream) {
    const float* x    = (const float*)d_in[0];
    const float* W_le = (const float*)d_in[1];
    const float* b_le = (const float*)d_in[2];
    const float* W_lr = (const float*)d_in[3];
    const float* b_lr = (const float*)d_in[4];
    const float* W_ge = (const float*)d_in[5];
    const float* b_ge = (const float*)d_in[6];
    const float* W_gn = (const float*)d_in[7];
    const float* b_gn = (const float*)d_in[8];
    float* out = (float*)d_out;

    cle_kernel<<<1024, 256, 0, stream>>>(x, W_le, b_le, W_lr, b_lr,
                                         W_ge, b_ge, W_gn, b_gn, out);
}

// Round 21
// 44.922 us; speedup vs baseline: 1.3889x; 1.3452x over previous
//
#include <hip/hip_runtime.h>

// CharacteristicLineEncoder: B=4096, DIM=3, L=300, S=60, P=5, E=128
// out[b,s,e] = sum_p W_lr[s,p]*relu(W_le[e,:]·x[b,:,5s+p] + b_le[e]) + b_lr[s]
//            + relu( sum_l W_gn[l]*relu(W_ge[e,:]·x[b,:,l] + b_ge[e]) + b_gn )
//
// R9 structure (best LDS-x kernel: 256 thr = 4 waves per b, lane owns
// e-pair, LDS-staged x read as broadcast ds_read_b128, two sweeps, stores
// interleaved per 4-region group in sweep 2) + NONTEMPORAL stores (R17's
// only proven win: out is never re-read, bypass L2 allocation).
// R20 fix: __builtin_nontemporal_store needs clang ext_vector_type, not
// HIP float2 -> v2f for stores (same bitwise layout). All proven mechanics
// kept: readfirstlane'd wq (R6), named accs / literal indices (rule #20),
// natural register allocation (R4/R5).

typedef float v2f __attribute__((ext_vector_type(2)));

#define RELU(v) fmaxf((v), 0.0f)

__global__ __launch_bounds__(256) void cle_kernel(
    const float* __restrict__ x,     // [B,3,300]
    const float* __restrict__ W_le,  // [E,3]
    const float* __restrict__ b_le,  // [E]
    const float* __restrict__ W_lr,  // [300]
    const float* __restrict__ b_lr,  // [60]
    const float* __restrict__ W_ge,  // [E,3]
    const float* __restrict__ b_ge,  // [E]
    const float* __restrict__ W_gn,  // [300]
    const float* __restrict__ b_gn,  // [1]
    float* __restrict__ out)         // [B,60,128]
{
    const int tid  = threadIdx.x;
    const int lane = tid & 63;
    const int wq   = __builtin_amdgcn_readfirstlane(tid >> 6);  // wave 0..3, SGPR
    const int b    = blockIdx.x;
    const int e0   = lane << 1;      // this lane's e-pair

    __shared__ __align__(16) float4 sx4[225];  // x[b]: channel c, quad j at [c*75+j]
    __shared__ float2 sgp[4][64];              // per-wave global-branch partials

    // ---- stage x[b] (3.6 KB), coalesced float4 ----
    if (tid < 225) sx4[tid] = ((const float4*)(x + (size_t)b * 900))[tid];

    // per-lane (e-pair) weights
    const float wg00 = W_ge[e0 * 3 + 0], wg01 = W_ge[e0 * 3 + 1], wg02 = W_ge[e0 * 3 + 2];
    const float wg10 = W_ge[e0 * 3 + 3], wg11 = W_ge[e0 * 3 + 4], wg12 = W_ge[e0 * 3 + 5];
    const float bg0 = b_ge[e0], bg1 = b_ge[e0 + 1];
    const float wl00 = W_le[e0 * 3 + 0], wl01 = W_le[e0 * 3 + 1], wl02 = W_le[e0 * 3 + 2];
    const float wl10 = W_le[e0 * 3 + 3], wl11 = W_le[e0 * 3 + 4], wl12 = W_le[e0 * 3 + 5];
    const float bl0 = b_le[e0], bl1 = b_le[e0 + 1];
    const float bgn = b_gn[0];

    __syncthreads();

    // ---- sweep 1: global branch over this wave's quads ----
    float ga0 = 0.f, ga1 = 0.f, ga2 = 0.f, ga3 = 0.f;   // e0
    float gb0 = 0.f, gb1 = 0.f, gb2 = 0.f, gb3 = 0.f;   // e1
#define GE0(cmp) RELU(fmaf(wg02, c2.cmp, fmaf(wg01, c1.cmp, fmaf(wg00, c0.cmp, bg0))))
#define GE1(cmp) RELU(fmaf(wg12, c2.cmp, fmaf(wg11, c1.cmp, fmaf(wg10, c0.cmp, bg1))))
    {
        const int qb = wq * 20;
        const int nq = (wq < 3) ? 20 : 15;   // SGPR
        for (int g = 0; g < 4; ++g) {
            if (g * 5 < nq) {                // wave-uniform guard
#pragma unroll
                for (int qi = 0; qi < 5; ++qi) {
                    const int qq = qb + g * 5 + qi;
                    const int l4 = qq * 4;   // uniform -> W_gn scalarizes
                    const float4 c0 = sx4[qq], c1 = sx4[75 + qq], c2 = sx4[150 + qq];
                    ga0 = fmaf(W_gn[l4 + 0], GE0(x), ga0);
                    gb0 = fmaf(W_gn[l4 + 0], GE1(x), gb0);
                    ga1 = fmaf(W_gn[l4 + 1], GE0(y), ga1);
                    gb1 = fmaf(W_gn[l4 + 1], GE1(y), gb1);
                    ga2 = fmaf(W_gn[l4 + 2], GE0(z), ga2);
                    gb2 = fmaf(W_gn[l4 + 2], GE1(z), gb2);
                    ga3 = fmaf(W_gn[l4 + 3], GE0(w), ga3);
                    gb3 = fmaf(W_gn[l4 + 3], GE1(w), gb3);
                }
            }
        }
    }
    sgp[wq][lane] = make_float2((ga0 + ga1) + (ga2 + ga3), (gb0 + gb1) + (gb2 + gb3));
    __syncthreads();

    float gf0, gf1;
    {
        const float2 p0 = sgp[0][lane], p1 = sgp[1][lane];
        const float2 p2 = sgp[2][lane], p3 = sgp[3][lane];
        gf0 = RELU(((p0.x + p1.x) + (p2.x + p3.x)) + bgn);
        gf1 = RELU(((p0.y + p1.y) + (p2.y + p3.y)) + bgn);
    }

    // ---- sweep 2: local branch; 4 NT stores after EACH 4-region group ----
    v2f* ob2 = (v2f*)(out + (size_t)b * (60 * 128)) + lane;   // + s*64

#define LE0(cmp) RELU(fmaf(wl02, c2.cmp, fmaf(wl01, c1.cmp, fmaf(wl00, c0.cmp, bl0))))
#define LE1(cmp) RELU(fmaf(wl12, c2.cmp, fmaf(wl11, c1.cmp, fmaf(wl10, c0.cmp, bl1))))
#define NTS(v0, v1, p)                                                         \
    {                                                                          \
        v2f _t; _t.x = (v0); _t.y = (v1);                                      \
        __builtin_nontemporal_store(_t, (p));                                  \
    }
#define DOQ(qi, R0, R1, R2, R3)                                                \
    {                                                                          \
        const int qq = q0 + (qi);                                              \
        const int lw = qq * 4;            /* uniform -> W_lr scalarizes */     \
        const float4 c0 = sx4[qq], c1 = sx4[75 + qq], c2 = sx4[150 + qq];      \
        a0##R0 = fmaf(W_lr[lw + 0], LE0(x), a0##R0);                           \
        a1##R0 = fmaf(W_lr[lw + 0], LE1(x), a1##R0);                           \
        a0##R1 = fmaf(W_lr[lw + 1], LE0(y), a0##R1);                           \
        a1##R1 = fmaf(W_lr[lw + 1], LE1(y), a1##R1);                           \
        a0##R2 = fmaf(W_lr[lw + 2], LE0(z), a0##R2);                           \
        a1##R2 = fmaf(W_lr[lw + 2], LE1(z), a1##R2);                           \
        a0##R3 = fmaf(W_lr[lw + 3], LE0(w), a0##R3);                           \
        a1##R3 = fmaf(W_lr[lw + 3], LE1(w), a1##R3);                           \
    }

    {
        const int ng = (wq < 3) ? 4 : 3;     // SGPR: groups of 4 regions
        for (int g = 0; g < 4; ++g) {
            if (g < ng) {                    // wave-uniform guard
                const int q0 = wq * 20 + g * 5;
                float a00 = 0.f, a01 = 0.f, a02 = 0.f, a03 = 0.f;  // e0
                float a10 = 0.f, a11 = 0.f, a12 = 0.f, a13 = 0.f;  // e1
                // element t = 4*qi + comp (l = 80wq + 20g + t), region = t/5
                DOQ(0, 0, 0, 0, 0)   // t 0..3
                DOQ(1, 0, 1, 1, 1)   // t 4..7
                DOQ(2, 1, 1, 2, 2)   // t 8..11
                DOQ(3, 2, 2, 2, 3)   // t 12..15
                DOQ(4, 3, 3, 3, 3)   // t 16..19

                const int s0 = wq * 16 + g * 4;   // uniform -> b_lr scalar
                NTS(a00 + gf0 + b_lr[s0 + 0], a10 + gf1 + b_lr[s0 + 0], &ob2[(s0 + 0) * 64]);
                NTS(a01 + gf0 + b_lr[s0 + 1], a11 + gf1 + b_lr[s0 + 1], &ob2[(s0 + 1) * 64]);
                NTS(a02 + gf0 + b_lr[s0 + 2], a12 + gf1 + b_lr[s0 + 2], &ob2[(s0 + 2) * 64]);
                NTS(a03 + gf0 + b_lr[s0 + 3], a13 + gf1 + b_lr[s0 + 3], &ob2[(s0 + 3) * 64]);
            }
        }
    }
}

extern "C" void kernel_launch(void* const* d_in, const int* in_sizes, int n_in,
                              void* d_out, int out_size, void* d_ws, size_t ws_size,
                              hipStream_t stream) {
    const float* x    = (const float*)d_in[0];
    const float* W_le = (const float*)d_in[1];
    const float* b_le = (const float*)d_in[2];
    const float* W_lr = (const float*)d_in[3];
    const float* b_lr = (const float*)d_in[4];
    const float* W_ge = (const float*)d_in[5];
    const float* b_ge = (const float*)d_in[6];
    const float* W_gn = (const float*)d_in[7];
    const float* b_gn = (const float*)d_in[8];
    float* out = (float*)d_out;

    cle_kernel<<<4096, 256, 0, stream>>>(x, W_le, b_le, W_lr, b_lr,
                                         W_ge, b_ge, W_gn, b_gn, out);
}